// Round 7
// baseline (113.784 us; speedup 1.0000x reference)
//
#include <hip/hip_runtime.h>

// B=8, C=128, H=W=64 -> N=4096 tokens/batch. d_qk=32.
// R7: R6 + (1) per-wave full-K staging + cross-barrier K-frag register
// prefetch, (2) setprio around PV MFMA cluster, (3) packed raw-layout
// partial-O (coalesced 16B stores) + rebuilt out_kernel (coalesced reads,
// LDS transpose, Wo GEMM). Split-K(4) gated on ws_size (fallback 2).

#define NB 8
#define CCH 128
#define NTOK 4096
#define DQK 32
#define KT 64
#define PARTSZ 4194304   // u16 per partial-O part (32768*128)

typedef __attribute__((ext_vector_type(8))) short bf16x8;
typedef __attribute__((ext_vector_type(4))) float f32x4;
typedef unsigned short u16;
typedef unsigned int u32;

static __device__ __forceinline__ f32x4 mfma16(bf16x8 a, bf16x8 b, f32x4 c) {
  return __builtin_amdgcn_mfma_f32_16x16x32_bf16(a, b, c, 0, 0, 0);
}
static __device__ __forceinline__ u16 f2bf(float f) {
  union { float f; u32 u; } cv; cv.f = f;
  u32 u = cv.u;
  u += 0x7fffu + ((u >> 16) & 1u);
  return (u16)(u >> 16);
}
static __device__ __forceinline__ float bf2f(u16 v) {
  union { u32 u; float f; } cv; cv.u = ((u32)v) << 16;
  return cv.f;
}
static __device__ __forceinline__ u32 cvtpk(float lo, float hi) {
  u32 d;
  asm("v_cvt_pk_bf16_f32 %0, %1, %2" : "=v"(d) : "v"(lo), "v"(hi));
  return d;
}
static __device__ __forceinline__ void gload16(const void* g, void* l) {
  __builtin_amdgcn_global_load_lds(
      (const __attribute__((address_space(1))) void*)g,
      (__attribute__((address_space(3))) void*)l, 16, 0, 0);
}

// ---------------- kernel 0: weights -> bf16 [320][128] ----------------------
__global__ __launch_bounds__(256) void wconv_kernel(
    const float* __restrict__ Wq, const float* __restrict__ Wk,
    const float* __restrict__ Wv, const float* __restrict__ Wo,
    u16* __restrict__ wcomb) {
  int idx = blockIdx.x * 256 + threadIdx.x;
  int r = idx >> 7;
  float v;
  if (r < 32)        v = Wq[idx];
  else if (r < 64)   v = Wk[idx - 4096];
  else if (r < 192)  v = Wv[idx - 8192];
  else               v = Wo[idx - 24576];
  wcomb[idx] = f2bf(v);
}

// ---------------- kernel 1: fused LayerNorm + QKV projection ----------------
__global__ __launch_bounds__(256) void lnqkv_kernel(
    const float* __restrict__ x, const float* __restrict__ gamma,
    const float* __restrict__ beta, const u16* __restrict__ wcomb,
    u16* __restrict__ Qg, u16* __restrict__ Kg, u16* __restrict__ Vt) {
  __shared__ float tile[128][64];
  __shared__ float red[2][4][64];
  __shared__ u16   xt[64][130];
  int t = threadIdx.x;
  int lane = t & 63, cq = t >> 6;
  int b = blockIdx.x >> 6;
  int posb = (blockIdx.x & 63) << 6;
  const float* xb = x + ((size_t)b * CCH) * NTOK + posb;
  for (int i = 0; i < 32; ++i) {
    int c = cq * 32 + i;
    tile[c][lane] = xb[(size_t)c * NTOK + lane];
  }
  __syncthreads();
  float s = 0.f, s2 = 0.f;
  for (int i = 0; i < 32; ++i) {
    float v = tile[cq * 32 + i][lane];
    s += v; s2 += v * v;
  }
  red[0][cq][lane] = s; red[1][cq][lane] = s2;
  __syncthreads();
  float mu  = (red[0][0][lane] + red[0][1][lane] + red[0][2][lane] + red[0][3][lane]) * (1.f / 128.f);
  float ex2 = (red[1][0][lane] + red[1][1][lane] + red[1][2][lane] + red[1][3][lane]) * (1.f / 128.f);
  float rstd = rsqrtf(ex2 - mu * mu + 1e-5f);
  for (int i = 0; i < 32; ++i) {
    int c = cq * 32 + i;
    float v = (tile[c][lane] - mu) * rstd * gamma[c] + beta[c];
    xt[lane][c] = f2bf(v);
  }
  __syncthreads();
  int w = t >> 6, row16 = lane & 15, kgrp = lane >> 4;
  bf16x8 af[4];
  for (int ks = 0; ks < 4; ++ks)
    af[ks] = *(const bf16x8*)&xt[w * 16 + row16][ks * 32 + kgrp * 8];
  f32x4 zero = {0.f, 0.f, 0.f, 0.f};
  f32x4 acc[12];
  for (int nt = 0; nt < 12; ++nt) {
    acc[nt] = zero;
    for (int ks = 0; ks < 4; ++ks) {
      bf16x8 bf = *(const bf16x8*)&wcomb[(size_t)(nt * 16 + row16) * CCH + ks * 32 + kgrp * 8];
      acc[nt] = mfma16(af[ks], bf, acc[nt]);
    }
  }
  int tok0 = b * NTOK + posb;
  for (int nt = 0; nt < 12; ++nt) {
    int col = nt * 16 + row16;
    for (int r = 0; r < 4; ++r) {
      int token = tok0 + w * 16 + kgrp * 4 + r;
      if (col < 32) {
        Qg[(size_t)token * DQK + col] = f2bf(acc[nt][r] * 1.44269504f);
      } else if (col < 64) {
        Kg[(size_t)token * DQK + (col - 32)] = f2bf(acc[nt][r]);
      } else {
        int tl = token & (NTOK - 1);
        int kp = (tl & ~31) | ((tl & 12) << 1) | ((tl & 16) >> 2) | (tl & 3);
        Vt[((size_t)b * CCH + (col - 64)) * NTOK + kp] = f2bf(acc[nt][r]);
      }
    }
  }
}

// ---------------- kernel 2: flash attention ---------------------------------
// 4 waves x 32q = 128 q/block; split-K(NS); grid 256*NS.
// K LDS (per tile, 4KB): key-pair rows, slot phys=(k>>1)*8+(((k&1)*4+f)^((k>>1)&7));
//   EACH wave stages the FULL K tile (duplicate writes) so its own vmcnt(0)
//   covers all of K -> next-tile K-frags prefetched to regs pre-barrier.
// V LDS (16KB): [c][8 slots of 16B], phys = c*64u16 + (s^(c&7))*8; V pre-permuted.
// l via ones-column MFMA. Partial O stored in packed raw lane layout:
//   [part][tok-block 32KB][wave 8KB][j 1KB][lane 16B], word i=sub*16+ntc*2+pr,
//   u32 = cvtpk(o[ntc][2pr], o[ntc][2pr+1]).
template <int NS>
__global__ __launch_bounds__(256, 4) void attn_kernel(
    const u16* __restrict__ Qg, const u16* __restrict__ Kg,
    const u16* __restrict__ Vt, u16* __restrict__ Op,
    float* __restrict__ lp) {
  __shared__ u16 lds[2][10240];   // per buf: K 2048 u16 (4KB) + V 8192 u16 (16KB)
  constexpr int KSEG = NTOK / NS;
  constexpr int NTILE = KSEG / KT;
  constexpr int BSH = (NS == 4) ? 7 : 6;
  int t = threadIdx.x;
  int w = t >> 6, lane = t & 63;
  int row16 = lane & 15, kgrp = lane >> 4;

  int cpx = (256 * NS) >> 3;
  int logical = (blockIdx.x & 7) * cpx + (blockIdx.x >> 3);  // XCD-chunked
  int qblk = logical & 31;
  int part = (logical >> 5) & (NS - 1);
  int b = logical >> BSH;
  int q0 = qblk * 128;
  int kt0 = part * KSEG;

  const u16* Qb = Qg + ((size_t)(b * NTOK + q0 + w * 32)) * DQK;
  bf16x8 qf0 = *(const bf16x8*)&Qb[(size_t)row16 * DQK + kgrp * 8];
  bf16x8 qf1 = *(const bf16x8*)&Qb[(size_t)(16 + row16) * DQK + kgrp * 8];

  bf16x8 ones_b;
  {
    short val = (row16 == 0) ? (short)0x3F80 : (short)0;
    for (int j = 0; j < 8; ++j) ones_b[j] = val;
  }

  // K staging (full tile per wave): lane constants
  int korig = (lane & 7) ^ (lane >> 3);
  int kconst = (((lane >> 3) * 2 + (korig >> 2)) * 32) + (korig & 3) * 8;
  const u16* ksrc = Kg + (size_t)(b * NTOK + kt0) * DQK + kconst;
  // V staging (quarter per wave)
  int cV = t >> 3;
  int sV = (t & 7) ^ (cV & 7);
  const u16* vsrc = Vt + ((size_t)b * CCH + cV) * NTOK + kt0 + sV * 8;
  int vdst = w * 512;

  f32x4 zero = {0.f, 0.f, 0.f, 0.f};
  f32x4 o0[8], o1[8], ol0, ol1;
#pragma unroll
  for (int i = 0; i < 8; ++i) { o0[i] = zero; o1[i] = zero; }
  ol0 = zero; ol1 = zero;

  auto stage = [&](int bi, int tile) {
    const u16* kp_ = ksrc + (size_t)tile * (KT * DQK);
#pragma unroll
    for (int ii = 0; ii < 4; ++ii)
      gload16(kp_ + ii * 512, &lds[bi][ii * 512]);
    const u16* vp_ = vsrc + tile * KT;
    gload16(vp_,          &lds[bi][2048 + vdst]);
    gload16(vp_ + 131072, &lds[bi][2048 + 2048 + vdst]);
    gload16(vp_ + 262144, &lds[bi][2048 + 4096 + vdst]);
    gload16(vp_ + 393216, &lds[bi][2048 + 6144 + vdst]);
  };

  auto loadK = [&](int bi, bf16x8* kf) {
#pragma unroll
    for (int nt = 0; nt < 4; ++nt) {
      int slot = (nt * 8 + (row16 >> 1)) * 8 +
                 ((((row16 & 1) << 2) + kgrp) ^ (row16 >> 1));
      kf[nt] = *(const bf16x8*)&lds[bi][slot * 8];
    }
  };

  auto compute = [&](int bi, const bf16x8* kf) {
    const u16* vb = &lds[bi][2048];
    f32x4 sa0[4], sa1[4];
#pragma unroll
    for (int nt = 0; nt < 4; ++nt) {
      sa0[nt] = mfma16(kf[nt], qf0, zero);
      sa1[nt] = mfma16(kf[nt], qf1, zero);
    }
#pragma unroll
    for (int nt = 0; nt < 4; ++nt)
      for (int r = 0; r < 4; ++r) {
        sa0[nt][r] = __builtin_amdgcn_exp2f(sa0[nt][r]);
        sa1[nt][r] = __builtin_amdgcn_exp2f(sa1[nt][r]);
      }
    union PU { u32 d[4]; bf16x8 v; };
    PU pf0[2], pf1[2];
#pragma unroll
    for (int ks = 0; ks < 2; ++ks) {
      pf0[ks].d[0] = cvtpk(sa0[2 * ks][0], sa0[2 * ks][1]);
      pf0[ks].d[1] = cvtpk(sa0[2 * ks][2], sa0[2 * ks][3]);
      pf0[ks].d[2] = cvtpk(sa0[2 * ks + 1][0], sa0[2 * ks + 1][1]);
      pf0[ks].d[3] = cvtpk(sa0[2 * ks + 1][2], sa0[2 * ks + 1][3]);
      pf1[ks].d[0] = cvtpk(sa1[2 * ks][0], sa1[2 * ks][1]);
      pf1[ks].d[1] = cvtpk(sa1[2 * ks][2], sa1[2 * ks][3]);
      pf1[ks].d[2] = cvtpk(sa1[2 * ks + 1][0], sa1[2 * ks + 1][1]);
      pf1[ks].d[3] = cvtpk(sa1[2 * ks + 1][2], sa1[2 * ks + 1][3]);
    }
    __builtin_amdgcn_s_setprio(1);
    ol0 = mfma16(pf0[0].v, ones_b, ol0);
    ol0 = mfma16(pf0[1].v, ones_b, ol0);
    ol1 = mfma16(pf1[0].v, ones_b, ol1);
    ol1 = mfma16(pf1[1].v, ones_b, ol1);
#pragma unroll
    for (int ks = 0; ks < 2; ++ks)
#pragma unroll
      for (int ntc = 0; ntc < 8; ++ntc) {
        int vslot = (ntc * 16 + row16) * 8 + (((ks << 2) + kgrp) ^ (row16 & 7));
        bf16x8 vf = *(const bf16x8*)&vb[vslot * 8];
        o0[ntc] = mfma16(pf0[ks].v, vf, o0[ntc]);
        o1[ntc] = mfma16(pf1[ks].v, vf, o1[ntc]);
      }
    __builtin_amdgcn_s_setprio(0);
  };

  bf16x8 kf[4];
  stage(0, 0);
  asm volatile("s_waitcnt vmcnt(0)" ::: "memory");
  loadK(0, kf);
  __builtin_amdgcn_s_barrier();
  int cur = 0;
  for (int tile = 0; tile < NTILE - 1; ++tile) {
    stage(cur ^ 1, tile + 1);
    compute(cur, kf);
    asm volatile("s_waitcnt vmcnt(0)" ::: "memory");
    loadK(cur ^ 1, kf);   // own wave staged FULL K(next) -> safe pre-barrier
    __builtin_amdgcn_s_barrier();
    cur ^= 1;
  }
  compute(cur, kf);

  // epilogue: packed raw-layout partial O (8 coalesced 16B stores/lane)
  u32 word[32];
#pragma unroll
  for (int sub = 0; sub < 2; ++sub) {
#pragma unroll
    for (int ntc = 0; ntc < 8; ++ntc) {
      f32x4 ov = sub ? o1[ntc] : o0[ntc];
      word[sub * 16 + ntc * 2]     = cvtpk(ov[0], ov[1]);
      word[sub * 16 + ntc * 2 + 1] = cvtpk(ov[2], ov[3]);
    }
  }
  u16* Opw = Op + (size_t)part * PARTSZ;
  size_t blkb = ((size_t)(b * NTOK + q0)) * CCH;
#pragma unroll
  for (int j = 0; j < 8; ++j) {
    uint4 v4;
    v4.x = word[4 * j]; v4.y = word[4 * j + 1];
    v4.z = word[4 * j + 2]; v4.w = word[4 * j + 3];
    *(uint4*)&Opw[blkb + w * 4096 + j * 512 + lane * 8] = v4;
  }
  int tokb = b * NTOK + q0 + w * 32;
  if (row16 == 0) {
#pragma unroll
    for (int r = 0; r < 4; ++r) {
      lp[part * 32768 + tokb + kgrp * 4 + r] = ol0[r];
      lp[part * 32768 + tokb + 16 + kgrp * 4 + r] = ol1[r];
    }
  }
}

// ---------------- kernel 3: combine parts + Wo GEMM + bias + residual -------
// 256 blocks x 128 tokens, thread mapping mirrors attn's raw layout.
__global__ __launch_bounds__(256) void out_kernel(
    const u16* __restrict__ Op, const float* __restrict__ lp, int ns,
    const u16* __restrict__ wcomb, const float* __restrict__ bo,
    const float* __restrict__ x, float* __restrict__ out) {
  __shared__ float lred[128];
  __shared__ u16 xt[128][132];
  int t = threadIdx.x;
  int w = t >> 6, lane = t & 63;
  int row16 = lane & 15, kgrp = lane >> 4;
  int blk = blockIdx.x;
  int tok0 = blk * 128;
  int b = tok0 >> 12, tloc = tok0 & (NTOK - 1);

  if (t < 128) {
    float s = 0.f;
    for (int p = 0; p < ns; ++p) s += lp[p * 32768 + tok0 + t];
    lred[t] = 1.f / s;
  }
  __syncthreads();
  float linv[2][4];
#pragma unroll
  for (int sub = 0; sub < 2; ++sub)
#pragma unroll
    for (int r = 0; r < 4; ++r)
      linv[sub][r] = lred[w * 32 + sub * 16 + kgrp * 4 + r];

  size_t blkb = (size_t)tok0 * CCH;
#pragma unroll
  for (int j = 0; j < 8; ++j) {
    float s[8] = {0.f, 0.f, 0.f, 0.f, 0.f, 0.f, 0.f, 0.f};
    for (int p = 0; p < ns; ++p) {
      uint4 v4 = *(const uint4*)&Op[(size_t)p * PARTSZ + blkb + w * 4096 + j * 512 + lane * 8];
      u32 ww[4] = {v4.x, v4.y, v4.z, v4.w};
#pragma unroll
      for (int m = 0; m < 4; ++m) {
        s[2 * m]     += bf2f((u16)(ww[m] & 0xffffu));
        s[2 * m + 1] += bf2f((u16)(ww[m] >> 16));
      }
    }
    int sub = j >> 2;
#pragma unroll
    for (int m = 0; m < 4; ++m) {
      int i = 4 * j + m;
      int ntc = (i >> 1) & 7, pr = i & 1;
      int c = ntc * 16 + row16;
#pragma unroll
      for (int dd = 0; dd < 2; ++dd) {
        int r = 2 * pr + dd;
        xt[w * 32 + sub * 16 + kgrp * 4 + r][c] = f2bf(s[2 * m + dd] * linv[sub][r]);
      }
    }
  }
  __syncthreads();

  f32x4 zero = {0.f, 0.f, 0.f, 0.f};
  f32x4 acc[2][8];
#pragma unroll
  for (int sub = 0; sub < 2; ++sub)
    for (int nt = 0; nt < 8; ++nt) acc[sub][nt] = zero;
#pragma unroll
  for (int ks = 0; ks < 4; ++ks) {
    bf16x8 af0 = *(const bf16x8*)&xt[w * 32 + row16][ks * 32 + kgrp * 8];
    bf16x8 af1 = *(const bf16x8*)&xt[w * 32 + 16 + row16][ks * 32 + kgrp * 8];
#pragma unroll
    for (int nt = 0; nt < 8; ++nt) {
      bf16x8 bfv = *(const bf16x8*)&wcomb[(size_t)(192 + nt * 16 + row16) * CCH + ks * 32 + kgrp * 8];
      acc[0][nt] = mfma16(af0, bfv, acc[0][nt]);
      acc[1][nt] = mfma16(af1, bfv, acc[1][nt]);
    }
  }
#pragma unroll
  for (int sub = 0; sub < 2; ++sub)
#pragma unroll
    for (int nt = 0; nt < 8; ++nt) {
      int cout = nt * 16 + row16;
      float bias = bo[cout];
      size_t base = ((size_t)b * CCH + cout) * NTOK + tloc + w * 32 + sub * 16 + kgrp * 4;
      float4 xr = *(const float4*)&x[base];
      float4 ov;
      ov.x = acc[sub][nt][0] + bias + xr.x;
      ov.y = acc[sub][nt][1] + bias + xr.y;
      ov.z = acc[sub][nt][2] + bias + xr.z;
      ov.w = acc[sub][nt][3] + bias + xr.w;
      *(float4*)&out[base] = ov;
    }
}

extern "C" void kernel_launch(void* const* d_in, const int* in_sizes, int n_in,
                              void* d_out, int out_size, void* d_ws, size_t ws_size,
                              hipStream_t stream) {
  const float* x     = (const float*)d_in[0];
  const float* gamma = (const float*)d_in[1];
  const float* beta  = (const float*)d_in[2];
  const float* Wq    = (const float*)d_in[3];
  const float* Wk    = (const float*)d_in[4];
  const float* Wv    = (const float*)d_in[5];
  const float* Wo    = (const float*)d_in[6];
  const float* bo    = (const float*)d_in[7];
  float* out = (float*)d_out;

  unsigned char* ws = (unsigned char*)d_ws;
  u16* Qg    = (u16*)(ws);                  //  2 MB
  u16* Kg    = (u16*)(ws + 2097152);        //  2 MB
  u16* Vt    = (u16*)(ws + 4194304);        //  8 MB [8][128][4096] key-permuted
  u16* wcomb = (u16*)(ws + 12582912);       //  80 KB
  float* lp  = (float*)(ws + 12664832);     //  ns*128 KB
  u16* Op    = (u16*)(ws + 13189120);       //  ns*8 MB raw-layout partials

  int ns = (ws_size >= 46743552u) ? 4 : 2;

  wconv_kernel<<<160, 256, 0, stream>>>(Wq, Wk, Wv, Wo, wcomb);
  lnqkv_kernel<<<512, 256, 0, stream>>>(x, gamma, beta, wcomb, Qg, Kg, Vt);
  if (ns == 4)
    attn_kernel<4><<<1024, 256, 0, stream>>>(Qg, Kg, Vt, Op, lp);
  else
    attn_kernel<2><<<512, 256, 0, stream>>>(Qg, Kg, Vt, Op, lp);
  out_kernel<<<256, 256, 0, stream>>>(Op, lp, ns, wcomb, bo, x, out);
}